// Round 4
// baseline (1263.829 us; speedup 1.0000x reference)
//
#include <hip/hip_runtime.h>

#define IN_F 48
#define EDGE_F 32
#define HID_F 128
#define OUT_F 64

// ---------------- counting-sort-by-dst preprocessing ----------------

__global__ void k_hist(const int* __restrict__ dst, int* __restrict__ cnt, int E) {
    int e = blockIdx.x * 256 + threadIdx.x;
    if (e < E) atomicAdd(&cnt[dst[e]], 1);
}

// inclusive scan of 1024-chunk -> offsets[1+g]; chunk totals -> blksum; zeroes cnt for reuse as cursor
__global__ void k_scan1(int* __restrict__ cnt, int* __restrict__ offsets,
                        int* __restrict__ blksum, int N) {
    __shared__ int sh[1024];
    int tid = threadIdx.x;
    int g = blockIdx.x * 1024 + tid;
    sh[tid] = (g < N) ? cnt[g] : 0;
    if (g < N) cnt[g] = 0;   // cursor reset folded in
    __syncthreads();
#pragma unroll
    for (int off = 1; off < 1024; off <<= 1) {
        int t = (tid >= off) ? sh[tid - off] : 0;
        __syncthreads();
        sh[tid] += t;
        __syncthreads();
    }
    if (g < N) offsets[1 + g] = sh[tid];
    if (tid == 1023) blksum[blockIdx.x] = sh[tid];
}

__global__ void k_scan2(int* __restrict__ blksum, int nb) {
    __shared__ int sh[256];
    int tid = threadIdx.x;
    int orig = (tid < nb) ? blksum[tid] : 0;
    sh[tid] = orig;
    __syncthreads();
#pragma unroll
    for (int off = 1; off < 256; off <<= 1) {
        int t = (tid >= off) ? sh[tid - off] : 0;
        __syncthreads();
        sh[tid] += t;
        __syncthreads();
    }
    if (tid < nb) blksum[tid] = sh[tid] - orig;  // exclusive
}

__global__ void k_scan3(int* __restrict__ offsets, const int* __restrict__ blksum, int N) {
    int g = blockIdx.x * 1024 + threadIdx.x;
    if (g < N) offsets[1 + g] += blksum[blockIdx.x];
    if (g == 0) offsets[0] = 0;
}

// ---------------- fused fill + edge encoder ----------------
// Edge-order: coalesced efeat stream; scattered full-line writes to msort[pos] (192B rows).
__global__ __launch_bounds__(256) void k_fill_msg(
    const float* __restrict__ efeat, const float* __restrict__ nfeat,
    const int* __restrict__ src, const int* __restrict__ dst,
    const int* __restrict__ offsets, int* __restrict__ cursor,
    const float* __restrict__ We, const float* __restrict__ be,
    int* __restrict__ srcs, float* __restrict__ msort, int E)
{
    int e = blockIdx.x * 256 + threadIdx.x;
    if (e >= E) return;
    int s = src[e], d = dst[e];
    int p = atomicAdd(&cursor[d], 1);          // issue early; latency overlaps compute
    int base = offsets[d];

    float ef[EDGE_F];
    const float4* ef4 = (const float4*)(efeat + (size_t)e * EDGE_F);
#pragma unroll
    for (int q = 0; q < EDGE_F / 4; ++q) {
        float4 v = ef4[q];
        ef[4 * q + 0] = v.x; ef[4 * q + 1] = v.y; ef[4 * q + 2] = v.z; ef[4 * q + 3] = v.w;
    }
    float acc[IN_F];
#pragma unroll
    for (int j = 0; j < IN_F; ++j) acc[j] = be[j];          // wave-uniform -> s_load
#pragma unroll
    for (int k = 0; k < EDGE_F; ++k) {
        float ek = ef[k];
#pragma unroll
        for (int j = 0; j < IN_F; ++j) acc[j] = fmaf(ek, We[k * IN_F + j], acc[j]);
    }

    int pos = base + p;
    srcs[pos] = s;
    const float4* n4 = (const float4*)(nfeat + (size_t)s * IN_F);
    float4* o4 = (float4*)(msort + (size_t)pos * IN_F);
#pragma unroll
    for (int q = 0; q < IN_F / 4; ++q) {
        float4 nv = n4[q];
        float4 ov;
        ov.x = fmaxf(acc[4 * q + 0], 0.0f) * nv.x;
        ov.y = fmaxf(acc[4 * q + 1], 0.0f) * nv.y;
        ov.z = fmaxf(acc[4 * q + 2], 0.0f) * nv.z;
        ov.w = fmaxf(acc[4 * q + 3], 0.0f) * nv.w;
        o4[q] = ov;
    }
}

// ---------------- layer-1 mean: pure stream over contiguous msort rows ----------------
__global__ __launch_bounds__(256) void k_gather48m(
    const float* __restrict__ msort, const int* __restrict__ offsets,
    float* __restrict__ hn0, int N) {
    int node = blockIdx.x * 4 + (threadIdx.x >> 6);
    int j = threadIdx.x & 63;
    if (node >= N) return;
    int jj = (j < IN_F) ? j : 0;
    int s0 = offsets[node], s1 = offsets[node + 1];
    float ivn = 1.0f / (float)max(s1 - s0, 1);
    float sum = 0.0f;
    int i = s0;
    for (; i + 4 <= s1; i += 4) {
        float a = msort[(size_t)(i + 0) * IN_F + jj];
        float b = msort[(size_t)(i + 1) * IN_F + jj];
        float c = msort[(size_t)(i + 2) * IN_F + jj];
        float d = msort[(size_t)(i + 3) * IN_F + jj];
        sum += (a + b) + (c + d);
    }
    for (; i < s1; ++i) sum += msort[(size_t)i * IN_F + jj];
    if (j < IN_F) hn0[(size_t)node * IN_F + j] = sum * ivn;
}

// ---------------- layer-2 neighbor mean: [nfeat, hn0], 96-wide, wave-per-node ----------------
// lane j owns col j; lanes j<32 additionally own col 64+j. 100% lane utilization.
__global__ __launch_bounds__(256) void k_gather96(
    const float* __restrict__ nfeat, const float* __restrict__ hn0,
    const int* __restrict__ srcs, const int* __restrict__ offsets,
    float* __restrict__ hn1m, int N) {
    int node = blockIdx.x * 4 + (threadIdx.x >> 6);
    int j = threadIdx.x & 63;
    if (node >= N) return;
    const float* tabA = (j < IN_F) ? (nfeat + j) : (hn0 + (j - IN_F));  // cols 0..63
    const float* tabB = hn0 + (j + 16);                                  // cols 64..95 (j<32)
    int s0 = offsets[node], s1 = offsets[node + 1];
    float ivn = 1.0f / (float)max(s1 - s0, 1);
    float sA = 0.0f, sB = 0.0f;
    int i = s0;
    for (; i + 4 <= s1; i += 4) {
        int sa = srcs[i], sb = srcs[i + 1], sc = srcs[i + 2], sd = srcs[i + 3];
        float a0 = tabA[(size_t)sa * IN_F], a1 = tabA[(size_t)sb * IN_F];
        float a2 = tabA[(size_t)sc * IN_F], a3 = tabA[(size_t)sd * IN_F];
        sA += (a0 + a1) + (a2 + a3);
        if (j < 32) {
            float b0 = tabB[(size_t)sa * IN_F], b1 = tabB[(size_t)sb * IN_F];
            float b2 = tabB[(size_t)sc * IN_F], b3 = tabB[(size_t)sd * IN_F];
            sB += (b0 + b1) + (b2 + b3);
        }
    }
    for (; i < s1; ++i) {
        int sa = srcs[i];
        sA += tabA[(size_t)sa * IN_F];
        if (j < 32) sB += tabB[(size_t)sa * IN_F];
    }
    hn1m[(size_t)node * 96 + j] = sA * ivn;
    if (j < 32) hn1m[(size_t)node * 96 + 64 + j] = sB * ivn;
}

// ---------------- layer-3 neighbor mean: h1, 128-wide ----------------
__global__ __launch_bounds__(256) void k_gather128(
    const float* __restrict__ h1, const int* __restrict__ srcs,
    const int* __restrict__ offsets, float* __restrict__ hn2, int N) {
    int node = blockIdx.x * 2 + (threadIdx.x >> 7);
    int j = threadIdx.x & 127;
    if (node >= N) return;
    int s0 = offsets[node], s1 = offsets[node + 1];
    float ivn = 1.0f / (float)max(s1 - s0, 1);
    float sum = 0.0f;
    int i = s0;
    for (; i + 4 <= s1; i += 4) {
        int sa = srcs[i], sb = srcs[i + 1], sc = srcs[i + 2], sd = srcs[i + 3];
        float va = h1[(size_t)sa * 128 + j];
        float vb = h1[(size_t)sb * 128 + j];
        float vc = h1[(size_t)sc * 128 + j];
        float vd = h1[(size_t)sd * 128 + j];
        sum += (va + vb) + (vc + vd);
    }
    for (; i < s1; ++i) sum += h1[(size_t)srcs[i] * 128 + j];
    hn2[(size_t)node * 128 + j] = sum * ivn;
}

// ---------------- node matmuls: 4 rows per wave (16 rows/block) ----------------
__global__ __launch_bounds__(256) void k_mm1(
    const float* __restrict__ nfeat, const float* __restrict__ hn0,
    const float* __restrict__ hn1m,
    const float* __restrict__ W1s, const float* __restrict__ W1n,
    const float* __restrict__ b1, float* __restrict__ h1, int N) {
    __shared__ float xs[16][192];
    int wv = threadIdx.x >> 6, lane = threadIdx.x & 63;
    int base = blockIdx.x * 16;
#pragma unroll
    for (int rr = 0; rr < 4; ++rr) {
        int row = base + wv * 4 + rr;
        int r = row < N ? row : N - 1;
        for (int k = lane; k < 192; k += 64) {
            float v;
            if (k < 48)      v = nfeat[(size_t)r * 48 + k];
            else if (k < 96) v = hn0[(size_t)r * 48 + (k - 48)];
            else             v = hn1m[(size_t)r * 96 + (k - 96)];
            xs[wv * 4 + rr][k] = v;
        }
    }
    __syncthreads();
    const float* x0 = xs[wv * 4 + 0];
    const float* x1 = xs[wv * 4 + 1];
    const float* x2 = xs[wv * 4 + 2];
    const float* x3 = xs[wv * 4 + 3];
    int c0 = lane, c1 = lane + 64;
    float a00 = b1[c0], a01 = b1[c1];
    float a10 = a00, a11 = a01, a20 = a00, a21 = a01, a30 = a00, a31 = a01;
#pragma unroll 4
    for (int k = 0; k < 96; ++k) {
        float w0 = W1s[k * 128 + c0], w1 = W1s[k * 128 + c1];
        a00 = fmaf(x0[k], w0, a00); a01 = fmaf(x0[k], w1, a01);
        a10 = fmaf(x1[k], w0, a10); a11 = fmaf(x1[k], w1, a11);
        a20 = fmaf(x2[k], w0, a20); a21 = fmaf(x2[k], w1, a21);
        a30 = fmaf(x3[k], w0, a30); a31 = fmaf(x3[k], w1, a31);
    }
#pragma unroll 4
    for (int k = 0; k < 96; ++k) {
        float w0 = W1n[k * 128 + c0], w1 = W1n[k * 128 + c1];
        a00 = fmaf(x0[96 + k], w0, a00); a01 = fmaf(x0[96 + k], w1, a01);
        a10 = fmaf(x1[96 + k], w0, a10); a11 = fmaf(x1[96 + k], w1, a11);
        a20 = fmaf(x2[96 + k], w0, a20); a21 = fmaf(x2[96 + k], w1, a21);
        a30 = fmaf(x3[96 + k], w0, a30); a31 = fmaf(x3[96 + k], w1, a31);
    }
    float accs[4][2] = {{a00, a01}, {a10, a11}, {a20, a21}, {a30, a31}};
#pragma unroll
    for (int rr = 0; rr < 4; ++rr) {
        int row = base + wv * 4 + rr;
        if (row < N) {
            h1[(size_t)row * 128 + c0] = fmaxf(accs[rr][0], 0.0f);
            h1[(size_t)row * 128 + c1] = fmaxf(accs[rr][1], 0.0f);
        }
    }
}

__global__ __launch_bounds__(256) void k_mm2(
    const float* __restrict__ h1, const float* __restrict__ hn2,
    const float* __restrict__ W2s, const float* __restrict__ W2n,
    const float* __restrict__ b2, float* __restrict__ out, int N) {
    __shared__ float xs[16][256];
    int wv = threadIdx.x >> 6, lane = threadIdx.x & 63;
    int base = blockIdx.x * 16;
#pragma unroll
    for (int rr = 0; rr < 4; ++rr) {
        int row = base + wv * 4 + rr;
        int r = row < N ? row : N - 1;
        for (int k = lane; k < 256; k += 64) {
            float v = (k < 128) ? h1[(size_t)r * 128 + k] : hn2[(size_t)r * 128 + (k - 128)];
            xs[wv * 4 + rr][k] = v;
        }
    }
    __syncthreads();
    const float* x0 = xs[wv * 4 + 0];
    const float* x1 = xs[wv * 4 + 1];
    const float* x2 = xs[wv * 4 + 2];
    const float* x3 = xs[wv * 4 + 3];
    float a0 = b2[lane], a1 = a0, a2 = a0, a3 = a0;
#pragma unroll 4
    for (int k = 0; k < 128; ++k) {
        float w = W2s[k * 64 + lane];
        a0 = fmaf(x0[k], w, a0); a1 = fmaf(x1[k], w, a1);
        a2 = fmaf(x2[k], w, a2); a3 = fmaf(x3[k], w, a3);
    }
#pragma unroll 4
    for (int k = 0; k < 128; ++k) {
        float w = W2n[k * 64 + lane];
        a0 = fmaf(x0[128 + k], w, a0); a1 = fmaf(x1[128 + k], w, a1);
        a2 = fmaf(x2[128 + k], w, a2); a3 = fmaf(x3[128 + k], w, a3);
    }
    float accs[4] = {a0, a1, a2, a3};
#pragma unroll
    for (int rr = 0; rr < 4; ++rr) {
        int row = base + wv * 4 + rr;
        if (row < N) out[(size_t)row * 64 + lane] = accs[rr];
    }
}

extern "C" void kernel_launch(void* const* d_in, const int* in_sizes, int n_in,
                              void* d_out, int out_size, void* d_ws, size_t ws_size,
                              hipStream_t stream) {
    const float* nfeat = (const float*)d_in[0];
    const float* efeat = (const float*)d_in[1];
    const int*   src   = (const int*)d_in[2];
    const int*   dst   = (const int*)d_in[3];
    const float* We    = (const float*)d_in[4];
    const float* be    = (const float*)d_in[5];
    const float* W1s   = (const float*)d_in[6];
    const float* W1n   = (const float*)d_in[7];
    const float* b1    = (const float*)d_in[8];
    const float* W2s   = (const float*)d_in[9];
    const float* W2n   = (const float*)d_in[10];
    const float* b2    = (const float*)d_in[11];
    float* out = (float*)d_out;

    int N = in_sizes[0] / IN_F;
    int E = in_sizes[2];

    // workspace layout (4B units):
    // cursor[N] | offsets[N+64] | blksum[256] | srcs[E] |
    // hn0[48N] | hn1m[96N] | h1[128N] | msort[48E]
    // hn2 aliases (hn0,hn1m) region (144N >= 128N), both dead after k_mm1.
    // Strictly smaller than round-2's layout (which fit), so no fallback needed.
    int*   cursor  = (int*)d_ws;
    int*   offsets = cursor + N;
    int*   blksum  = offsets + N + 64;
    int*   srcs    = blksum + 256;
    float* hn0     = (float*)(srcs + E);
    float* hn1m    = hn0 + (size_t)48 * N;
    float* h1      = hn1m + (size_t)96 * N;
    float* msort   = h1 + (size_t)128 * N;
    float* hn2     = hn0;  // alias

    int nb = (N + 1023) / 1024;  // 98 for N=100000 (<=256 required by k_scan2)

    hipMemsetAsync(cursor, 0, (size_t)N * sizeof(int), stream);
    k_hist<<<(E + 255) / 256, 256, 0, stream>>>(dst, cursor, E);
    k_scan1<<<nb, 1024, 0, stream>>>(cursor, offsets, blksum, N);   // also re-zeros cursor
    k_scan2<<<1, 256, 0, stream>>>(blksum, nb);
    k_scan3<<<nb, 1024, 0, stream>>>(offsets, blksum, N);

    k_fill_msg<<<(E + 255) / 256, 256, 0, stream>>>(efeat, nfeat, src, dst, offsets, cursor,
                                                    We, be, srcs, msort, E);
    k_gather48m<<<(N + 3) / 4, 256, 0, stream>>>(msort, offsets, hn0, N);
    k_gather96<<<(N + 3) / 4, 256, 0, stream>>>(nfeat, hn0, srcs, offsets, hn1m, N);
    k_mm1<<<(N + 15) / 16, 256, 0, stream>>>(nfeat, hn0, hn1m, W1s, W1n, b1, h1, N);
    k_gather128<<<(N + 1) / 2, 256, 0, stream>>>(h1, srcs, offsets, hn2, N);
    k_mm2<<<(N + 15) / 16, 256, 0, stream>>>(h1, hn2, W2s, W2n, b2, out, N);
}